// Round 1
// baseline (2084.450 us; speedup 1.0000x reference)
//
#include <hip/hip_runtime.h>
#include <hip/hip_bf16.h>
#include <stdint.h>

#define B_SZ 4
#define T_SZ 2048
#define D_SZ 1024

constexpr int BM = 32;     // Q rows per block
constexpr int BN = 64;     // KV rows per s-tile
constexpr int DC = 64;     // D chunk for K staging
constexpr int NTH = 512;   // 8 waves

typedef short bf16x8 __attribute__((ext_vector_type(8)));
typedef float f32x4 __attribute__((ext_vector_type(4)));

// bf16 bits of +-1 with sign = sign(x) ^ sign(s)
__device__ __forceinline__ uint32_t sbf(uint32_t xu, uint32_t su) {
  return 0x3F80u | (((xu ^ su) >> 16) & 0x8000u);
}

__global__ __launch_bounds__(NTH) void hdc_attn_kernel(
    const float* __restrict__ x, const float* __restrict__ bvq,
    const float* __restrict__ bvk, const float* __restrict__ bvv,
    float* __restrict__ out) {
  // rows padded by 16B so b128 frag reads/writes are bank-optimal
  __shared__ ushort Qs[BM][1032];   // 66048 B : Q tile as +-1 bf16
  __shared__ ushort Ks[BN][72];     //  9216 B : K chunk as +-1 bf16
  __shared__ ushort Ps[BM][72];     //  4608 B : sigmoid probs bf16

  const int tid = threadIdx.x;
  const int lane = tid & 63;
  const int w = tid >> 6;
  const int rg = w >> 2;   // 0..1 : 16-row group
  const int cg = w & 3;    // 0..3 : col group (16 s-cols for QK, 256 d-cols for PV)
  const int l15 = lane & 15;
  const int l4 = lane >> 4;

  const int b = blockIdx.x >> 6;        // T/BM = 64 tiles per batch
  const int ti = blockIdx.x & 63;
  const int t0 = ti * BM;

  // ---- stage Q tile as +-1 bf16 (coalesced float4 reads) ----
  {
    const float4* xr = (const float4*)(x + ((size_t)b * T_SZ + t0) * D_SZ);
    const float4* bq4 = (const float4*)bvq;
#pragma unroll
    for (int i = 0; i < 16; ++i) {
      int flat4 = tid + i * NTH;        // 0..8191
      int row = flat4 >> 8;             // 256 float4 per row
      int c4 = flat4 & 255;
      float4 v = xr[row * 256 + c4];
      float4 q = bq4[c4];
      uint32_t q0 = sbf(__float_as_uint(v.x), __float_as_uint(q.x));
      uint32_t q1 = sbf(__float_as_uint(v.y), __float_as_uint(q.y));
      uint32_t q2 = sbf(__float_as_uint(v.z), __float_as_uint(q.z));
      uint32_t q3 = sbf(__float_as_uint(v.w), __float_as_uint(q.w));
      *(uint2*)&Qs[row][c4 * 4] = make_uint2(q0 | (q1 << 16), q2 | (q3 << 16));
    }
  }

  // per-lane V sign flips for this wave's 16 d-columns x 16 n-blocks
  uint32_t vsign[16];
#pragma unroll
  for (int f = 0; f < 16; ++f)
    vsign[f] = __float_as_uint(bvv[cg * 256 + f * 16 + l15]) & 0x80000000u;

  f32x4 acc[16];
#pragma unroll
  for (int f = 0; f < 16; ++f) acc[f] = (f32x4){0.f, 0.f, 0.f, 0.f};

  const int nt = (t0 + BM + BN - 1) / BN;   // causal s-tile count

  for (int st = 0; st < nt; ++st) {
    const int s0 = st * BN;
    f32x4 sacc = (f32x4){0.f, 0.f, 0.f, 0.f};

    // ---- QK^T over D in 64-wide chunks ----
    for (int dc = 0; dc < D_SZ / DC; ++dc) {
      __syncthreads();   // prev Ks/Ps readers done
      {
        const int s = tid >> 3;
        const int c8 = (tid & 7) * 8;
        const float* xk = x + ((size_t)b * T_SZ + s0 + s) * D_SZ + dc * DC + c8;
        const float* bk = bvk + dc * DC + c8;
        float4 v0 = *(const float4*)xk;
        float4 v1 = *(const float4*)(xk + 4);
        float4 k0 = *(const float4*)bk;
        float4 k1 = *(const float4*)(bk + 4);
        uint32_t w0 = sbf(__float_as_uint(v0.x), __float_as_uint(k0.x)) |
                      (sbf(__float_as_uint(v0.y), __float_as_uint(k0.y)) << 16);
        uint32_t w1 = sbf(__float_as_uint(v0.z), __float_as_uint(k0.z)) |
                      (sbf(__float_as_uint(v0.w), __float_as_uint(k0.w)) << 16);
        uint32_t w2 = sbf(__float_as_uint(v1.x), __float_as_uint(k1.x)) |
                      (sbf(__float_as_uint(v1.y), __float_as_uint(k1.y)) << 16);
        uint32_t w3 = sbf(__float_as_uint(v1.z), __float_as_uint(k1.z)) |
                      (sbf(__float_as_uint(v1.w), __float_as_uint(k1.w)) << 16);
        *(uint4*)&Ks[s][c8] = make_uint4(w0, w1, w2, w3);
      }
      __syncthreads();
#pragma unroll
      for (int h = 0; h < 2; ++h) {
        bf16x8 a = *(const bf16x8*)&Qs[rg * 16 + l15][dc * DC + h * 32 + l4 * 8];
        bf16x8 kb = *(const bf16x8*)&Ks[cg * 16 + l15][h * 32 + l4 * 8];
        sacc = __builtin_amdgcn_mfma_f32_16x16x32_bf16(a, kb, sacc, 0, 0, 0);
      }
    }

    // ---- causal mask + sigmoid -> Ps (bf16) ----
    {
      const int scol = cg * 16 + l15;
      const int sg = s0 + scol;
#pragma unroll
      for (int r = 0; r < 4; ++r) {
        const int m = rg * 16 + l4 * 4 + r;
        float p = 0.f;
        if (sg <= t0 + m) p = 1.f / (1.f + __expf(-0.125f * sacc[r]));
        Ps[m][scol] = (ushort)(__float_as_uint(p) >> 16);
      }
    }
    __syncthreads();

    // ---- PV: acc += P (16xBN) * V (BN x 256-slice) ----
    const float* xv = x + ((size_t)b * T_SZ + s0) * D_SZ;
#pragma unroll
    for (int kk = 0; kk < 2; ++kk) {
      bf16x8 pa = *(const bf16x8*)&Ps[rg * 16 + l15][kk * 32 + l4 * 8];
      const float* xvs = xv + (size_t)(kk * 32 + l4 * 8) * D_SZ;
#pragma unroll
      for (int f = 0; f < 16; ++f) {
        const int n = cg * 256 + f * 16 + l15;
        const float* xn = xvs + n;
        bf16x8 vb;
#pragma unroll
        for (int i = 0; i < 8; ++i) {
          uint32_t u = __float_as_uint(xn[(size_t)i * D_SZ]) ^ vsign[f];
          vb[i] = (short)(u >> 16);
        }
        acc[f] = __builtin_amdgcn_mfma_f32_16x16x32_bf16(pa, vb, acc[f], 0, 0, 0);
      }
    }
  }

  // ---- write out (f32) ----
  float* orow = out + ((size_t)b * T_SZ + t0) * D_SZ;
#pragma unroll
  for (int f = 0; f < 16; ++f) {
    const int n = cg * 256 + f * 16 + l15;
#pragma unroll
    for (int r = 0; r < 4; ++r) {
      const int m = rg * 16 + l4 * 4 + r;
      orow[(size_t)m * D_SZ + n] = acc[f][r];
    }
  }
}

extern "C" void kernel_launch(void* const* d_in, const int* in_sizes, int n_in,
                              void* d_out, int out_size, void* d_ws, size_t ws_size,
                              hipStream_t stream) {
  const float* x = (const float*)d_in[0];
  const float* bvq = (const float*)d_in[1];
  const float* bvk = (const float*)d_in[2];
  const float* bvv = (const float*)d_in[3];
  float* out = (float*)d_out;

  dim3 grid(B_SZ * (T_SZ / BM));   // 256 blocks
  dim3 block(NTH);
  hipLaunchKernelGGL(hdc_attn_kernel, grid, block, 0, stream,
                     x, bvq, bvk, bvv, out);
}

// Round 2
// 373.495 us; speedup vs baseline: 5.5809x; 5.5809x over previous
//
#include <hip/hip_runtime.h>
#include <hip/hip_bf16.h>
#include <stdint.h>

#define B_SZ 4
#define T_SZ 2048
#define D_SZ 1024

constexpr int BM = 32;     // Q rows per block
constexpr int BN = 64;     // KV rows per s-tile
constexpr int NTH = 512;   // 8 waves

typedef short bf16x8 __attribute__((ext_vector_type(8)));
typedef float f32x4 __attribute__((ext_vector_type(4)));
typedef int i32x4 __attribute__((ext_vector_type(4)));
typedef unsigned short ushort8 __attribute__((ext_vector_type(8)));

__device__ __forceinline__ uint32_t sbf(uint32_t xu, uint32_t su) {
  return 0x3F80u | (((xu ^ su) >> 16) & 0x8000u);
}

__device__ __forceinline__ ushort f2bf(float f) {  // RNE f32->bf16
  uint32_t u = __float_as_uint(f);
  return (ushort)((u + 0x7FFFu + ((u >> 16) & 1u)) >> 16);
}

// ============================ PREP KERNEL =============================
// Qb,Kb: int8 sign(x)*sign(bq/bk) in [B][T][D].  Vt: bf16 x*sign(bv) in [B][D][T].
__global__ __launch_bounds__(256) void prep_kernel(
    const float* __restrict__ x, const float* __restrict__ bvq,
    const float* __restrict__ bvk, const float* __restrict__ bvv,
    char* __restrict__ Qb, char* __restrict__ Kb, ushort* __restrict__ Vt) {
  __shared__ ushort vt[64][72];
  const int bid = blockIdx.x;
  const int dt = bid & 15;         // 16 d-tiles of 64
  const int tt = (bid >> 4) & 31;  // 32 t-tiles of 64
  const int b = bid >> 9;
  const int t0 = tt * 64, d0 = dt * 64;
  const int tid = threadIdx.x;

#pragma unroll
  for (int p = 0; p < 4; ++p) {
    const int row = p * 16 + (tid >> 4);
    const int c4 = tid & 15;
    const size_t idx = ((size_t)(b * T_SZ + t0 + row)) * D_SZ + d0 + c4 * 4;
    float4 v = *(const float4*)(x + idx);
    float4 q = *(const float4*)(bvq + d0 + c4 * 4);
    float4 k = *(const float4*)(bvk + d0 + c4 * 4);
    float4 s = *(const float4*)(bvv + d0 + c4 * 4);
    uint32_t xu[4] = {__float_as_uint(v.x), __float_as_uint(v.y),
                      __float_as_uint(v.z), __float_as_uint(v.w)};
    uint32_t qu[4] = {__float_as_uint(q.x), __float_as_uint(q.y),
                      __float_as_uint(q.z), __float_as_uint(q.w)};
    uint32_t ku[4] = {__float_as_uint(k.x), __float_as_uint(k.y),
                      __float_as_uint(k.z), __float_as_uint(k.w)};
    uint32_t su[4] = {__float_as_uint(s.x), __float_as_uint(s.y),
                      __float_as_uint(s.z), __float_as_uint(s.w)};
    uint32_t qw = 0, kw = 0;
#pragma unroll
    for (int j = 0; j < 4; ++j) {
      uint32_t qb = ((xu[j] ^ qu[j]) & 0x80000000u) ? 0xFFu : 0x01u;
      uint32_t kb = ((xu[j] ^ ku[j]) & 0x80000000u) ? 0xFFu : 0x01u;
      qw |= qb << (8 * j);
      kw |= kb << (8 * j);
      vt[row][c4 * 4 + j] = f2bf(__uint_as_float(xu[j] ^ (su[j] & 0x80000000u)));
    }
    *(uint32_t*)(Qb + idx) = qw;
    *(uint32_t*)(Kb + idx) = kw;
  }
  __syncthreads();
#pragma unroll
  for (int p = 0; p < 2; ++p) {
    const int dr = p * 32 + (tid >> 3);
    const int tc = tid & 7;
    ushort8 o;
#pragma unroll
    for (int j = 0; j < 8; ++j) o[j] = vt[tc * 8 + j][dr];
    *(ushort8*)(Vt + ((size_t)(b * D_SZ + d0 + dr)) * T_SZ + t0 + tc * 8) = o;
  }
}

// ============================ MAIN KERNEL =============================
// grid = B * 64 tiles * 2 halves; each block does half the causal s-tiles of
// one 32-row Q tile and atomicAdds its partial P*V into zeroed out.
__global__ __launch_bounds__(NTH, 4) void attn_main(
    const char* __restrict__ Qb, const char* __restrict__ Kb,
    const ushort* __restrict__ Vt, float* __restrict__ out) {
  __shared__ __align__(16) unsigned char Qs[BM][1040];  // 33.3 KB, +16B pad
  __shared__ __align__(16) ushort Ps[BM][72];           // 4.6 KB

  const int tid = threadIdx.x;
  const int lane = tid & 63;
  const int w = tid >> 6;
  const int rg = w >> 2;  // 0..1 : 16-row group
  const int cg = w & 3;   // 0..3 : 16 s-cols (QK) / 256 d-cols (PV)
  const int l15 = lane & 15;
  const int l4 = lane >> 4;

  const int bid = blockIdx.x;
  const int half = bid & 1;
  const int ti = (bid >> 1) & 63;
  const int b = bid >> 7;
  const int t0 = ti * BM;

  // ---- stage Q tile (i8) into LDS, coalesced 16B ----
  {
    const int row = tid >> 4;
    const int c = (tid & 15) * 64;
    const uint4* src = (const uint4*)(Qb + ((size_t)(b * T_SZ + t0 + row)) * D_SZ + c);
    uint4 a0 = src[0], a1 = src[1], a2 = src[2], a3 = src[3];
    *(uint4*)&Qs[row][c] = a0;
    *(uint4*)&Qs[row][c + 16] = a1;
    *(uint4*)&Qs[row][c + 32] = a2;
    *(uint4*)&Qs[row][c + 48] = a3;
  }
  __syncthreads();

  const int nt = (t0 + BM + BN - 1) / BN;  // causal s-tile count
  const int s_beg = half ? (nt + 1) / 2 : 0;
  const int s_end = half ? nt : (nt + 1) / 2;

  f32x4 acc[16];
#pragma unroll
  for (int f = 0; f < 16; ++f) acc[f] = (f32x4){0.f, 0.f, 0.f, 0.f};

  const unsigned char* qrow = &Qs[rg * 16 + l15][l4 * 16];

  for (int st = s_beg; st < s_end; ++st) {
    const int s0 = st * BN;
    i32x4 sacc = (i32x4){0, 0, 0, 0};

    // ---- QK^T: K frags straight from global (L2-resident), Q from LDS ----
    const char* kbase = Kb + ((size_t)(b * T_SZ + s0 + cg * 16 + l15)) * D_SZ + l4 * 16;
#pragma unroll
    for (int kc = 0; kc < 16; ++kc) {
      i32x4 a = *(const i32x4*)(qrow + kc * 64);
      i32x4 kf = *(const i32x4*)(kbase + kc * 64);
      sacc = __builtin_amdgcn_mfma_i32_16x16x64_i8(a, kf, sacc, 0, 0, 0);
    }

    __syncthreads();  // prev-iter Ps readers done
    {
      const int scol = cg * 16 + l15;
      const int sg = s0 + scol;
#pragma unroll
      for (int r = 0; r < 4; ++r) {
        const int m = rg * 16 + l4 * 4 + r;
        float p = 0.f;
        if (sg <= t0 + m) p = 1.f / (1.f + __expf(-0.125f * (float)sacc[r]));
        Ps[m][scol] = f2bf(p);
      }
    }
    __syncthreads();

    // ---- PV: V frags contiguous from transposed Vt ----
    const ushort* vtb = Vt + ((size_t)(b * D_SZ + cg * 256)) * T_SZ + s0;
#pragma unroll
    for (int kk = 0; kk < 2; ++kk) {
      bf16x8 pa = *(const bf16x8*)&Ps[rg * 16 + l15][kk * 32 + l4 * 8];
      const ushort* vks = vtb + kk * 32 + l4 * 8;
#pragma unroll
      for (int f = 0; f < 16; ++f) {
        bf16x8 vb = *(const bf16x8*)(vks + (size_t)(f * 16 + l15) * T_SZ);
        acc[f] = __builtin_amdgcn_mfma_f32_16x16x32_bf16(pa, vb, acc[f], 0, 0, 0);
      }
    }
  }

  // ---- accumulate into out (exactly 2 commutative adds per element) ----
  float* orow = out + ((size_t)(b * T_SZ + t0)) * D_SZ;
#pragma unroll
  for (int f = 0; f < 16; ++f) {
    const int n = cg * 256 + f * 16 + l15;
#pragma unroll
    for (int r = 0; r < 4; ++r) {
      const int m = rg * 16 + l4 * 4 + r;
      atomicAdd(orow + (size_t)m * D_SZ + n, acc[f][r]);
    }
  }
}

// ===================== FALLBACK (round-1 kernel, if ws too small) =====
__global__ __launch_bounds__(NTH) void hdc_attn_fallback(
    const float* __restrict__ x, const float* __restrict__ bvq,
    const float* __restrict__ bvk, const float* __restrict__ bvv,
    float* __restrict__ out) {
  __shared__ ushort Qs[BM][1032];
  __shared__ ushort Ks[BN][72];
  __shared__ ushort Ps[BM][72];
  const int tid = threadIdx.x;
  const int lane = tid & 63;
  const int w = tid >> 6;
  const int rg = w >> 2, cg = w & 3;
  const int l15 = lane & 15, l4 = lane >> 4;
  const int b = blockIdx.x >> 6;
  const int ti = blockIdx.x & 63;
  const int t0 = ti * BM;
  {
    const float4* xr = (const float4*)(x + ((size_t)b * T_SZ + t0) * D_SZ);
    const float4* bq4 = (const float4*)bvq;
#pragma unroll
    for (int i = 0; i < 16; ++i) {
      int flat4 = tid + i * NTH;
      int row = flat4 >> 8, c4 = flat4 & 255;
      float4 v = xr[row * 256 + c4];
      float4 q = bq4[c4];
      uint32_t q0 = sbf(__float_as_uint(v.x), __float_as_uint(q.x));
      uint32_t q1 = sbf(__float_as_uint(v.y), __float_as_uint(q.y));
      uint32_t q2 = sbf(__float_as_uint(v.z), __float_as_uint(q.z));
      uint32_t q3 = sbf(__float_as_uint(v.w), __float_as_uint(q.w));
      *(uint2*)&Qs[row][c4 * 4] = make_uint2(q0 | (q1 << 16), q2 | (q3 << 16));
    }
  }
  uint32_t vsign[16];
#pragma unroll
  for (int f = 0; f < 16; ++f)
    vsign[f] = __float_as_uint(bvv[cg * 256 + f * 16 + l15]) & 0x80000000u;
  f32x4 acc[16];
#pragma unroll
  for (int f = 0; f < 16; ++f) acc[f] = (f32x4){0.f, 0.f, 0.f, 0.f};
  const int nt = (t0 + BM + BN - 1) / BN;
  for (int st = 0; st < nt; ++st) {
    const int s0 = st * BN;
    f32x4 sacc = (f32x4){0.f, 0.f, 0.f, 0.f};
    for (int dc = 0; dc < D_SZ / 64; ++dc) {
      __syncthreads();
      {
        const int s = tid >> 3;
        const int c8 = (tid & 7) * 8;
        const float* xk = x + ((size_t)b * T_SZ + s0 + s) * D_SZ + dc * 64 + c8;
        const float* bk = bvk + dc * 64 + c8;
        float4 v0 = *(const float4*)xk;
        float4 v1 = *(const float4*)(xk + 4);
        float4 k0 = *(const float4*)bk;
        float4 k1 = *(const float4*)(bk + 4);
        uint32_t w0 = sbf(__float_as_uint(v0.x), __float_as_uint(k0.x)) |
                      (sbf(__float_as_uint(v0.y), __float_as_uint(k0.y)) << 16);
        uint32_t w1 = sbf(__float_as_uint(v0.z), __float_as_uint(k0.z)) |
                      (sbf(__float_as_uint(v0.w), __float_as_uint(k0.w)) << 16);
        uint32_t w2 = sbf(__float_as_uint(v1.x), __float_as_uint(k1.x)) |
                      (sbf(__float_as_uint(v1.y), __float_as_uint(k1.y)) << 16);
        uint32_t w3 = sbf(__float_as_uint(v1.z), __float_as_uint(k1.z)) |
                      (sbf(__float_as_uint(v1.w), __float_as_uint(k1.w)) << 16);
        *(uint4*)&Ks[s][c8] = make_uint4(w0, w1, w2, w3);
      }
      __syncthreads();
#pragma unroll
      for (int h = 0; h < 2; ++h) {
        bf16x8 a = *(const bf16x8*)&Qs[rg * 16 + l15][dc * 64 + h * 32 + l4 * 8];
        bf16x8 kb = *(const bf16x8*)&Ks[cg * 16 + l15][h * 32 + l4 * 8];
        sacc = __builtin_amdgcn_mfma_f32_16x16x32_bf16(a, kb, sacc, 0, 0, 0);
      }
    }
    {
      const int scol = cg * 16 + l15;
      const int sg = s0 + scol;
#pragma unroll
      for (int r = 0; r < 4; ++r) {
        const int m = rg * 16 + l4 * 4 + r;
        float p = 0.f;
        if (sg <= t0 + m) p = 1.f / (1.f + __expf(-0.125f * sacc[r]));
        Ps[m][scol] = (ushort)(__float_as_uint(p) >> 16);
      }
    }
    __syncthreads();
    const float* xv = x + ((size_t)b * T_SZ + s0) * D_SZ;
#pragma unroll
    for (int kk = 0; kk < 2; ++kk) {
      bf16x8 pa = *(const bf16x8*)&Ps[rg * 16 + l15][kk * 32 + l4 * 8];
      const float* xvs = xv + (size_t)(kk * 32 + l4 * 8) * D_SZ;
#pragma unroll
      for (int f = 0; f < 16; ++f) {
        const int n = cg * 256 + f * 16 + l15;
        const float* xn = xvs + n;
        bf16x8 vb;
#pragma unroll
        for (int i = 0; i < 8; ++i) {
          uint32_t u = __float_as_uint(xn[(size_t)i * D_SZ]) ^ vsign[f];
          vb[i] = (short)(u >> 16);
        }
        acc[f] = __builtin_amdgcn_mfma_f32_16x16x32_bf16(pa, vb, acc[f], 0, 0, 0);
      }
    }
  }
  float* orow = out + ((size_t)b * T_SZ + t0) * D_SZ;
#pragma unroll
  for (int f = 0; f < 16; ++f) {
    const int n = cg * 256 + f * 16 + l15;
#pragma unroll
    for (int r = 0; r < 4; ++r) {
      const int m = rg * 16 + l4 * 4 + r;
      orow[(size_t)m * D_SZ + n] = acc[f][r];
    }
  }
}

extern "C" void kernel_launch(void* const* d_in, const int* in_sizes, int n_in,
                              void* d_out, int out_size, void* d_ws, size_t ws_size,
                              hipStream_t stream) {
  const float* x = (const float*)d_in[0];
  const float* bvq = (const float*)d_in[1];
  const float* bvk = (const float*)d_in[2];
  const float* bvv = (const float*)d_in[3];
  float* out = (float*)d_out;

  const size_t QB_SZ = (size_t)B_SZ * T_SZ * D_SZ;        // 8 MB (i8)
  const size_t NEED = QB_SZ * 2 + QB_SZ * 2;              // Qb + Kb + Vt(bf16) = 32 MB

  if (ws_size >= NEED) {
    char* Qb = (char*)d_ws;
    char* Kb = Qb + QB_SZ;
    ushort* Vt = (ushort*)(Kb + QB_SZ);
    hipLaunchKernelGGL(prep_kernel, dim3(B_SZ * 32 * 16), dim3(256), 0, stream,
                       x, bvq, bvk, bvv, Qb, Kb, Vt);
    hipMemsetAsync(out, 0, (size_t)out_size * sizeof(float), stream);
    hipLaunchKernelGGL(attn_main, dim3(B_SZ * 64 * 2), dim3(NTH), 0, stream,
                       Qb, Kb, Vt, out);
  } else {
    hipLaunchKernelGGL(hdc_attn_fallback, dim3(B_SZ * 64), dim3(NTH), 0, stream,
                       x, bvq, bvk, bvv, out);
  }
}